// Round 12
// baseline (99.261 us; speedup 1.0000x reference)
//
#include <hip/hip_runtime.h>
#include <hip/hip_bf16.h>

#define B_SENT 128
#define L_TOK  256
#define D_DIM  1024
#define TM     16              // tokens per block (16 tiles per sentence)

typedef __attribute__((ext_vector_type(8))) short bf16x8;
typedef __attribute__((ext_vector_type(4))) float f32x4;

__device__ __forceinline__ unsigned short f2bf(float f) {
    return __builtin_bit_cast(unsigned short, __float2bfloat16(f));
}
__device__ __forceinline__ float softplus_f(float x) {
    float ax = fabsf(x);
    return fmaxf(x, 0.0f) + __logf(1.0f + __expf(-ax));
}
__device__ __forceinline__ bf16x8 cvt8f(const f32x4& lo, const f32x4& hi) {
    bf16x8 u;
    u[0] = (short)f2bf(lo[0]); u[1] = (short)f2bf(lo[1]);
    u[2] = (short)f2bf(lo[2]); u[3] = (short)f2bf(lo[3]);
    u[4] = (short)f2bf(hi[0]); u[5] = (short)f2bf(hi[1]);
    u[6] = (short)f2bf(hi[2]); u[7] = (short)f2bf(hi[3]);
    return u;
}

// ---------------------------------------------------------------------------
// Pre-pack glob (f32) -> bf16 MFMA B-fragments, BK=32 chunks (512 KB total):
// packed[((side*32+kb)*512 + n*64 + lane)*8 + e]
//   = glob[side][n*16+(lane&15)][kb*32+(lane>>4)*8+e]
// ---------------------------------------------------------------------------
__global__ __launch_bounds__(256) void pack_g_kernel(
    const float* __restrict__ g0, const float* __restrict__ g1,
    short* __restrict__ packed)
{
    const int idx  = blockIdx.x * 256 + threadIdx.x;   // 0..32767
    const int lane = idx & 63;
    const int n    = (idx >> 6) & 7;
    const int kb   = (idx >> 9) & 31;
    const int side = idx >> 14;
    const int row  = n * 16 + (lane & 15);
    const int col  = kb * 32 + (lane >> 4) * 8;
    const float* g = side ? g1 : g0;
    const f32x4 v0 = *reinterpret_cast<const f32x4*>(&g[(size_t)row * D_DIM + col]);
    const f32x4 v1 = *reinterpret_cast<const f32x4*>(&g[(size_t)row * D_DIM + col + 4]);
    *reinterpret_cast<bf16x8*>(&packed[(size_t)idx * 8]) = cvt8f(v0, v1);
}

// ---------------------------------------------------------------------------
// Main "flat-K": block = 512 threads (8 waves), 16 tokens x 128 sentences.
// Wave w owns K-slice [w*128, w*128+128): holds its B panel in REGISTERS
// (4 sub-k x 8 n-frags = 128 VGPR), issues all 8 A float4 loads up front,
// runs 32 MFMAs with no barriers, then a 3-level LDS tree combines the 8
// K-slices and wave 0 applies the masked softplus epilogue.
// ---------------------------------------------------------------------------
__global__ __launch_bounds__(512, 2) void mi_main_kernel(
    const float* __restrict__ tok0, const float* __restrict__ tok1,
    const int* __restrict__ len0, const int* __restrict__ len1,
    const short* __restrict__ packed, float* __restrict__ acc_ws)
{
    const int side = blockIdx.y;
    const float* tok = side ? tok1 : tok0;
    const int*   len = side ? len1 : len0;

    const int tile   = blockIdx.x;       // 0..2047
    const int b_sent = tile >> 4;        // 16 tiles per sentence
    const int toff   = (tile & 15) * TM;
    const int count  = max(1, len[b_sent]) - toff;
    if (count <= 0) return;              // uniform whole-block exit
    const int tb     = b_sent * L_TOK + toff;

    const int tid  = threadIdx.x;
    const int wave = tid >> 6;           // 0..7 = K-slice
    const int lane = tid & 63;
    const int lrow = lane & 15;
    const int kgrp = lane >> 4;

    // ---- B panel for this wave's K-slice: 32 x 16B register loads ----
    const short* bchunk = packed + ((size_t)side * 32 + wave * 4) * 4096;
    bf16x8 Bk[4][8];
#pragma unroll
    for (int s = 0; s < 4; ++s)
#pragma unroll
        for (int n = 0; n < 8; ++n)
            Bk[s][n] = *reinterpret_cast<const bf16x8*>(
                bchunk + (size_t)s * 4096 + (n * 64 + lane) * 8);

    // ---- A: 8 independent float4 loads (16 rows x this wave's 128 K) ----
    const int arow = min(lrow, count - 1);   // clamp masked rows (cache hit)
    const float* asrc = tok + (size_t)(tb + arow) * D_DIM + wave * 128 + kgrp * 8;
    f32x4 Alo[4], Ahi[4];
#pragma unroll
    for (int s = 0; s < 4; ++s) {
        Alo[s] = *reinterpret_cast<const f32x4*>(asrc + s * 32);
        Ahi[s] = *reinterpret_cast<const f32x4*>(asrc + s * 32 + 4);
    }

    // ---- 32 MFMAs, 8 independent acc chains, no barriers ----
    f32x4 acc[8];
#pragma unroll
    for (int n = 0; n < 8; ++n) acc[n] = (f32x4){0.f, 0.f, 0.f, 0.f};
#pragma unroll
    for (int s = 0; s < 4; ++s) {
        const bf16x8 af = cvt8f(Alo[s], Ahi[s]);
#pragma unroll
        for (int n = 0; n < 8; ++n)
            acc[n] = __builtin_amdgcn_mfma_f32_16x16x32_bf16(af, Bk[s][n], acc[n], 0, 0, 0);
    }

    // ---- combine the 8 K-slices: 3-level LDS tree ----
    __shared__ f32x4 cl[4][64][9];       // [9] stride: 144 B -> 8-way max alias
    if (wave >= 4) {
#pragma unroll
        for (int n = 0; n < 8; ++n) cl[wave - 4][lane][n] = acc[n];
    }
    __syncthreads();
    if (wave < 4) {
#pragma unroll
        for (int n = 0; n < 8; ++n) {
            f32x4 o = cl[wave][lane][n];
            acc[n][0] += o[0]; acc[n][1] += o[1]; acc[n][2] += o[2]; acc[n][3] += o[3];
        }
    }
    __syncthreads();
    if (wave == 2 || wave == 3) {
#pragma unroll
        for (int n = 0; n < 8; ++n) cl[wave - 2][lane][n] = acc[n];
    }
    __syncthreads();
    if (wave < 2) {
#pragma unroll
        for (int n = 0; n < 8; ++n) {
            f32x4 o = cl[wave][lane][n];
            acc[n][0] += o[0]; acc[n][1] += o[1]; acc[n][2] += o[2]; acc[n][3] += o[3];
        }
    }
    __syncthreads();
    if (wave == 1) {
#pragma unroll
        for (int n = 0; n < 8; ++n) cl[0][lane][n] = acc[n];
    }
    __syncthreads();

    // ---- epilogue (wave 0 only): masked softplus + wave reduce + atomic ----
    if (wave == 0) {
        float ep = 0.f, en = 0.f;
#pragma unroll
        for (int n = 0; n < 8; ++n) {
            f32x4 o = cl[0][lane][n];
            const int g = n * 16 + lrow;           // sentence id (frag col)
#pragma unroll
            for (int j = 0; j < 4; ++j) {
                const int rl = kgrp * 4 + j;       // local token row 0..15
                if (rl < count) {
                    float res = acc[n][j] + o[j];
                    float sp  = softplus_f(res);
                    if (g == b_sent) ep += res - sp;   // -softplus(-res)
                    else             en += sp;         // softplus(-res)+res
                }
            }
        }
#pragma unroll
        for (int off = 32; off; off >>= 1) {
            ep += __shfl_down(ep, off);
            en += __shfl_down(en, off);
        }
        if (lane == 0) {
            atomicAdd(&acc_ws[side * 2 + 0], ep);
            atomicAdd(&acc_ws[side * 2 + 1], en);
        }
    }
}

__global__ void mi_finalize_kernel(const int* __restrict__ len0,
                                   const int* __restrict__ len1,
                                   const float* __restrict__ acc_ws,
                                   float* __restrict__ out)
{
    const int lane = threadIdx.x;   // 1 wave
    int s0 = 0, s1 = 0;
    for (int i = lane; i < B_SENT; i += 64) {
        s0 += max(1, len0[i]);
        s1 += max(1, len1[i]);
    }
#pragma unroll
    for (int off = 32; off; off >>= 1) {
        s0 += __shfl_down(s0, off);
        s1 += __shfl_down(s1, off);
    }
    if (lane == 0) {
        const float num_nodes = (float)(s0 + s1);
        const float ep = acc_ws[0] + acc_ws[2];
        const float en = acc_ws[1] + acc_ws[3];
        out[0] = en / (num_nodes * (float)(B_SENT - 1)) - ep / num_nodes;
        out[1] = ((float)s0 + (float)s1) / (2.0f * (float)B_SENT);
    }
}

extern "C" void kernel_launch(void* const* d_in, const int* in_sizes, int n_in,
                              void* d_out, int out_size, void* d_ws, size_t ws_size,
                              hipStream_t stream) {
    const float* tok0  = (const float*)d_in[0];
    const float* tok1  = (const float*)d_in[1];
    const float* glob0 = (const float*)d_in[2];
    const float* glob1 = (const float*)d_in[3];
    const int*   len0  = (const int*)d_in[4];
    const int*   len1  = (const int*)d_in[5];
    float* out = (float*)d_out;

    float* acc    = (float*)d_ws;                       // 4 floats @ offset 0
    short* packed = (short*)((char*)d_ws + 256);        // 512 KB bf16 fragments

    hipMemsetAsync(d_ws, 0, 256, stream);
    pack_g_kernel<<<128, 256, 0, stream>>>(glob0, glob1, packed);

    dim3 grid(32768 / TM, 2);   // 2048 token-tiles x 2 sides
    mi_main_kernel<<<grid, 512, 0, stream>>>(tok0, tok1, len0, len1, packed, acc);
    mi_finalize_kernel<<<1, 64, 0, stream>>>(len0, len1, acc, out);
}